// Round 3
// baseline (1145.242 us; speedup 1.0000x reference)
//
#include <hip/hip_runtime.h>
#include <stdint.h>

#define N_NODES 50000
#define N_EDGES 800000

typedef unsigned int uint32;

// ---------- bf16 helpers ----------
__device__ inline float bflo(uint32 u) { return __builtin_bit_cast(float, u << 16); }
__device__ inline float bfhi(uint32 u) { return __builtin_bit_cast(float, u & 0xffff0000u); }
__device__ inline float bf2f(unsigned short h) { return __builtin_bit_cast(float, (uint32)h << 16); }
__device__ inline unsigned short f2bf(float f) {
    uint32 u = __builtin_bit_cast(uint32, f);
    u += 0x7fffu + ((u >> 16) & 1u);  // RNE
    return (unsigned short)(u >> 16);
}
__device__ inline uint32 pack2(float lo, float hi) {
    return (uint32)f2bf(lo) | ((uint32)f2bf(hi) << 16);
}

// ---------- CSR build ----------
__global__ __launch_bounds__(256) void zero_k(int* p, int n) {
    int i = blockIdx.x * 256 + threadIdx.x;
    if (i < n) p[i] = 0;
}

__global__ __launch_bounds__(256) void count_k(const int* __restrict__ ei, int* __restrict__ cnt) {
    int e = blockIdx.x * 256 + threadIdx.x;
    if (e < N_EDGES) atomicAdd(&cnt[ei[N_EDGES + e]], 1);
}

__global__ __launch_bounds__(1024) void scan_k(int* __restrict__ cnt, int* __restrict__ rowptr) {
    __shared__ int sh[1024];
    const int CH = 49;  // 1024*49 = 50176 >= 50000
    int t = threadIdx.x;
    int base = t * CH;
    int s = 0;
    for (int i = 0; i < CH; i++) {
        int idx = base + i;
        if (idx < N_NODES) s += cnt[idx];
    }
    sh[t] = s;
    __syncthreads();
    for (int d = 1; d < 1024; d <<= 1) {
        int v = (t >= d) ? sh[t - d] : 0;
        __syncthreads();
        sh[t] += v;
        __syncthreads();
    }
    int run = sh[t] - s;
    for (int i = 0; i < CH; i++) {
        int idx = base + i;
        if (idx < N_NODES) {
            int v = cnt[idx];
            rowptr[idx] = run;
            cnt[idx] = run;  // cursor copy
            run += v;
        }
    }
    if (t == 1023) rowptr[N_NODES] = sh[1023];
}

__global__ __launch_bounds__(256) void fill_k(const int* __restrict__ ei, int* __restrict__ cursor,
                                              int* __restrict__ csr) {
    int e = blockIdx.x * 256 + threadIdx.x;
    if (e < N_EDGES) {
        int d = ei[N_EDGES + e];
        int p = atomicAdd(&cursor[d], 1);
        csr[p] = ei[e];  // src
    }
}

// ---------- weight prep: W fp32 [k][n] -> Whi/Wlo bf16 [n][k] (hi+lo split) ----------
__global__ __launch_bounds__(256) void wprep_k(const float* __restrict__ W,
                                               unsigned short* __restrict__ Whi,
                                               unsigned short* __restrict__ Wlo) {
    int idx = blockIdx.x * 256 + threadIdx.x;  // 262144
    int k = idx >> 9, n = idx & 511;
    float w = W[idx];
    unsigned short hi = f2bf(w);
    float lo = w - bf2f(hi);
    Whi[n * 512 + k] = hi;
    Wlo[n * 512 + k] = f2bf(lo);
}

// ---------- x fp32 -> bf16 packed ----------
__global__ __launch_bounds__(256) void xconv_k(const float* __restrict__ x, uint32* __restrict__ xb) {
    int i = blockIdx.x * 256 + threadIdx.x;  // 12.8M
    float2 v = ((const float2*)x)[i];
    xb[i] = pack2(v.x, v.y);
}

// ---------- aggregation: h[dst] = sum_{src} feat[src] + (1+eps)*feat[dst]  (bf16 in/out, fp32 acc)
__global__ __launch_bounds__(256) void agg_k(const uint32* __restrict__ xin,
                                             const int* __restrict__ rowptr,
                                             const int* __restrict__ csr,
                                             const float* __restrict__ eps,
                                             uint32* __restrict__ hout) {
    int node = blockIdx.x;
    int t = threadIdx.x;
    int beg = rowptr[node], end = rowptr[node + 1];
    const uint32* xc = xin + t;
    float a0 = 0.f, a1 = 0.f;
    int e = beg;
    for (; e + 4 <= end; e += 4) {
        int n0 = csr[e], n1 = csr[e + 1], n2 = csr[e + 2], n3 = csr[e + 3];
        uint32 u0 = xc[n0 * 256], u1 = xc[n1 * 256], u2 = xc[n2 * 256], u3 = xc[n3 * 256];
        a0 += bflo(u0) + bflo(u1) + bflo(u2) + bflo(u3);
        a1 += bfhi(u0) + bfhi(u1) + bfhi(u2) + bfhi(u3);
    }
    for (; e < end; ++e) {
        uint32 u = xc[csr[e] * 256];
        a0 += bflo(u);
        a1 += bfhi(u);
    }
    float ep = 1.0f + eps[0];
    uint32 us = xc[node * 256];
    float h0 = fmaf(ep, bflo(us), a0);
    float h1 = fmaf(ep, bfhi(us), a1);
    hout[node * 256 + t] = pack2(h0, h1);
}

// ---------- GEMM: relu(A[M,512](bf16) @ W[512,512] + b(fp32)) ----------
// W given as bf16 [n][k] (Whi, + Wlo if SPLIT). Out: bf16 (outB) or fp32 (outF).
typedef __bf16 bf16x8 __attribute__((ext_vector_type(8)));
typedef float f32x4 __attribute__((ext_vector_type(4)));

template <bool SPLIT, bool F32OUT>
__global__ __launch_bounds__(256) void gemm_k(const unsigned short* __restrict__ A,
                                              const unsigned short* __restrict__ Whi,
                                              const unsigned short* __restrict__ Wlo,
                                              const float* __restrict__ bias,
                                              unsigned short* __restrict__ outB,
                                              float* __restrict__ outF, int M) {
    constexpr int K = 512, N = 512, BK = 32, TM = 128;
    __shared__ unsigned short lds_a[TM * BK];
    __shared__ unsigned short lds_bh[TM * BK];
    __shared__ unsigned short lds_bl[SPLIT ? TM * BK : 16];
    const int t = threadIdx.x;
    const int w = t >> 6, lane = t & 63;
    const int wrow = w >> 1, wcol = w & 1;
    const int m0 = blockIdx.y * TM;
    const int n0 = blockIdx.x * TM;

    int r0 = t >> 2, cc = (t & 3) * 8;
    int r1 = 64 + r0;
    int am0 = m0 + r0; am0 = am0 < M ? am0 : M - 1;
    int am1 = m0 + r1; am1 = am1 < M ? am1 : M - 1;
    const unsigned short* ag0 = A + (size_t)am0 * K + cc;
    const unsigned short* ag1 = A + (size_t)am1 * K + cc;
    const unsigned short* bh0 = Whi + (size_t)(n0 + r0) * K + cc;
    const unsigned short* bh1 = Whi + (size_t)(n0 + r1) * K + cc;
    const unsigned short* bl0 = Wlo + (size_t)(n0 + r0) * K + cc;
    const unsigned short* bl1 = Wlo + (size_t)(n0 + r1) * K + cc;

    f32x4 acc[4][4] = {};
    const int quad = lane >> 4, l15 = lane & 15;
    const int arow = wrow * 64 + l15;
    const int brow = wcol * 64 + l15;

    for (int k0 = 0; k0 < K; k0 += BK) {
        uint4 va0 = *(const uint4*)(ag0 + k0);
        uint4 va1 = *(const uint4*)(ag1 + k0);
        uint4 vh0 = *(const uint4*)(bh0 + k0);
        uint4 vh1 = *(const uint4*)(bh1 + k0);
        uint4 vl0, vl1;
        if (SPLIT) {
            vl0 = *(const uint4*)(bl0 + k0);
            vl1 = *(const uint4*)(bl1 + k0);
        }
        __syncthreads();  // previous iteration's LDS reads complete
        *(uint4*)&lds_a[r0 * BK + cc] = va0;
        *(uint4*)&lds_a[r1 * BK + cc] = va1;
        *(uint4*)&lds_bh[r0 * BK + cc] = vh0;
        *(uint4*)&lds_bh[r1 * BK + cc] = vh1;
        if (SPLIT) {
            *(uint4*)&lds_bl[r0 * BK + cc] = vl0;
            *(uint4*)&lds_bl[r1 * BK + cc] = vl1;
        }
        __syncthreads();
        bf16x8 af[4], bh[4], bl[4];
#pragma unroll
        for (int i = 0; i < 4; i++)
            af[i] = *(const bf16x8*)&lds_a[(arow + i * 16) * BK + quad * 8];
#pragma unroll
        for (int j = 0; j < 4; j++)
            bh[j] = *(const bf16x8*)&lds_bh[(brow + j * 16) * BK + quad * 8];
        if (SPLIT) {
#pragma unroll
            for (int j = 0; j < 4; j++)
                bl[j] = *(const bf16x8*)&lds_bl[(brow + j * 16) * BK + quad * 8];
        }
#pragma unroll
        for (int i = 0; i < 4; i++)
#pragma unroll
            for (int j = 0; j < 4; j++) {
                acc[i][j] = __builtin_amdgcn_mfma_f32_16x16x32_bf16(af[i], bh[j], acc[i][j], 0, 0, 0);
                if (SPLIT)
                    acc[i][j] = __builtin_amdgcn_mfma_f32_16x16x32_bf16(af[i], bl[j], acc[i][j], 0, 0, 0);
            }
    }

    // epilogue: C/D mapping col(n) = lane&15, row(m) = quad*4 + reg
#pragma unroll
    for (int j = 0; j < 4; j++) {
        int n = n0 + wcol * 64 + j * 16 + l15;
        float bv = bias[n];
#pragma unroll
        for (int i = 0; i < 4; i++) {
            int mbase = m0 + wrow * 64 + i * 16 + quad * 4;
#pragma unroll
            for (int r = 0; r < 4; r++) {
                int m = mbase + r;
                if (m < M) {
                    float v = fmaxf(acc[i][j][r] + bv, 0.0f);
                    if (F32OUT) outF[(size_t)m * N + n] = v;
                    else        outB[(size_t)m * N + n] = f2bf(v);
                }
            }
        }
    }
}

// ---------- L2 normalize (bf16 in/out, in-place safe): one wave per node ----------
__global__ __launch_bounds__(256) void l2norm_k(const uint32* __restrict__ z, uint32* __restrict__ out) {
    int node = blockIdx.x * 4 + (threadIdx.x >> 6);
    int lane = threadIdx.x & 63;
    const uint4* zp = (const uint4*)(z + (size_t)node * 256);
    uint4 q = zp[lane];
    float f0 = bflo(q.x), f1 = bfhi(q.x), f2 = bflo(q.y), f3 = bfhi(q.y);
    float f4 = bflo(q.z), f5 = bfhi(q.z), f6 = bflo(q.w), f7 = bfhi(q.w);
    float ss = f0 * f0 + f1 * f1 + f2 * f2 + f3 * f3 + f4 * f4 + f5 * f5 + f6 * f6 + f7 * f7;
#pragma unroll
    for (int off = 32; off > 0; off >>= 1) ss += __shfl_xor(ss, off);
    float inv = 1.0f / fmaxf(sqrtf(ss), 1e-12f);
    uint4 o;
    o.x = pack2(f0 * inv, f1 * inv);
    o.y = pack2(f2 * inv, f3 * inv);
    o.z = pack2(f4 * inv, f5 * inv);
    o.w = pack2(f6 * inv, f7 * inv);
    ((uint4*)(out + (size_t)node * 256))[lane] = o;
}

// ---------- softmax over 512 classes (fp32): logits already in d_out; write probs ----------
__global__ __launch_bounds__(256) void softmax_k(const float* __restrict__ logits,
                                                 float* __restrict__ probs) {
    int node = blockIdx.x * 4 + (threadIdx.x >> 6);
    int lane = threadIdx.x & 63;
    const float4* zp = (const float4*)(logits + (size_t)node * 512);
    float4 q0 = zp[lane * 2], q1 = zp[lane * 2 + 1];
    float f[8] = {q0.x, q0.y, q0.z, q0.w, q1.x, q1.y, q1.z, q1.w};
    float m = f[0];
#pragma unroll
    for (int i = 1; i < 8; i++) m = fmaxf(m, f[i]);
#pragma unroll
    for (int off = 32; off > 0; off >>= 1) m = fmaxf(m, __shfl_xor(m, off));
    float e[8], s = 0.f;
#pragma unroll
    for (int i = 0; i < 8; i++) { e[i] = __expf(f[i] - m); s += e[i]; }
#pragma unroll
    for (int off = 32; off > 0; off >>= 1) s += __shfl_xor(s, off);
    float inv = 1.0f / s;
    float4* pp = (float4*)(probs + (size_t)node * 512);
    pp[lane * 2]     = make_float4(e[0] * inv, e[1] * inv, e[2] * inv, e[3] * inv);
    pp[lane * 2 + 1] = make_float4(e[4] * inv, e[5] * inv, e[6] * inv, e[7] * inv);
}

// ---------- host launch ----------
extern "C" void kernel_launch(void* const* d_in, const int* in_sizes, int n_in,
                              void* d_out, int out_size, void* d_ws, size_t ws_size,
                              hipStream_t stream) {
    (void)in_sizes; (void)n_in; (void)out_size; (void)ws_size;
    const float* x = (const float*)d_in[0];
    const int* ei = (const int*)d_in[1];
    const float* W1 = (const float*)d_in[2];
    const float* b1 = (const float*)d_in[3];
    const float* e1 = (const float*)d_in[4];
    const float* W2 = (const float*)d_in[5];
    const float* b2 = (const float*)d_in[6];
    const float* e2 = (const float*)d_in[7];
    const float* W3 = (const float*)d_in[8];
    const float* b3 = (const float*)d_in[9];
    const float* e3 = (const float*)d_in[10];
    float* out = (float*)d_out;                      // logits[50000*512] ++ probs[50000*512]
    float* out_logits = out;
    float* out_probs = out + (size_t)N_NODES * 512;

    // workspace layout (~109 MB)
    char* ws = (char*)d_ws;
    int* rowptr = (int*)ws;                          // 50048 ints
    int* cursor = rowptr + 50048;                    // 50048 ints
    int* csr = cursor + 50048;                       // 800000 ints
    unsigned short* Wsp = (unsigned short*)(csr + N_EDGES);  // 3 layers x (hi 256K + lo 256K) shorts
    unsigned short* featA = Wsp + 3 * 524288;        // 25.6M shorts (51.2 MB)
    unsigned short* featB = featA + (size_t)N_NODES * 512;  // 25.6M shorts

    // CSR build
    zero_k<<<196, 256, 0, stream>>>(cursor, N_NODES);
    count_k<<<(N_EDGES + 255) / 256, 256, 0, stream>>>(ei, cursor);
    scan_k<<<1, 1024, 0, stream>>>(cursor, rowptr);
    fill_k<<<(N_EDGES + 255) / 256, 256, 0, stream>>>(ei, cursor, csr);

    // weight prep (hi/lo bf16, transposed to [n][k])
    wprep_k<<<1024, 256, 0, stream>>>(W1, Wsp,           Wsp + 262144);
    wprep_k<<<1024, 256, 0, stream>>>(W2, Wsp + 524288,  Wsp + 786432);
    wprep_k<<<1024, 256, 0, stream>>>(W3, Wsp + 1048576, Wsp + 1310720);

    // x -> bf16
    xconv_k<<<50000, 256, 0, stream>>>(x, (uint32*)featB);

    dim3 ggrid(4, (N_NODES + 127) / 128);

    // layer 1
    agg_k<<<N_NODES, 256, 0, stream>>>((const uint32*)featB, rowptr, csr, e1, (uint32*)featA);
    gemm_k<false, false><<<ggrid, 256, 0, stream>>>(featA, Wsp, Wsp + 262144, b1, featB, nullptr, N_NODES);
    l2norm_k<<<N_NODES / 4, 256, 0, stream>>>((const uint32*)featB, (uint32*)featB);
    // layer 2
    agg_k<<<N_NODES, 256, 0, stream>>>((const uint32*)featB, rowptr, csr, e2, (uint32*)featA);
    gemm_k<false, false><<<ggrid, 256, 0, stream>>>(featA, Wsp + 524288, Wsp + 786432, b2, featB, nullptr, N_NODES);
    l2norm_k<<<N_NODES / 4, 256, 0, stream>>>((const uint32*)featB, (uint32*)featB);
    // layer 3: split-precision GEMM, fp32 logits straight to d_out
    agg_k<<<N_NODES, 256, 0, stream>>>((const uint32*)featB, rowptr, csr, e3, (uint32*)featA);
    gemm_k<true, true><<<ggrid, 256, 0, stream>>>(featA, Wsp + 1048576, Wsp + 1310720, b3, nullptr, out_logits, N_NODES);
    // softmax -> probs
    softmax_k<<<N_NODES / 4, 256, 0, stream>>>(out_logits, out_probs);
}